// Round 1
// baseline (334.287 us; speedup 1.0000x reference)
//
#include <hip/hip_runtime.h>

// Problem constants (from reference): T=2048, B=8, IN=1024, OUT=1024, N_MODULES=16, K=2
#define T_DIM   2048
#define B_DIM   8
#define IN_DIM  1024
#define OUT_DIM 1024
#define NMOD    16
#define KSLOT   2

// GEMM tiling (m97 structure): 128x128 block tile, BK=32, 4 waves of 64x64
#define BM 128
#define BN 128
#define BK 32

typedef __bf16 bf16x8 __attribute__((ext_vector_type(8)));
typedef float  f32x4  __attribute__((ext_vector_type(4)));

typedef const __attribute__((address_space(1))) void* gptr_t;
typedef __attribute__((address_space(3))) void* lptr_t;

__device__ __forceinline__ void async_load16(const void* gp, void* lp) {
  __builtin_amdgcn_global_load_lds((gptr_t)gp, (lptr_t)lp, 16, 0, 0);
}

// fp32 -> bf16 round-to-nearest-even (data has no NaNs; skip NaN special-case)
__device__ __forceinline__ unsigned short f2bf_rne(float f) {
  unsigned int u = __float_as_uint(f);
  u += 0x7fffu + ((u >> 16) & 1u);
  return (unsigned short)(u >> 16);
}

// Prepass: repack x [T][B][IN] fp32 -> xb [B][T][IN] bf16, convert weight -> wb bf16 (same layout).
__global__ __launch_bounds__(256) void convert_repack(
    const float* __restrict__ x, const float* __restrict__ w,
    unsigned short* __restrict__ xb, unsigned short* __restrict__ wb) {
  long tid = (long)blockIdx.x * blockDim.x + threadIdx.x;
  const long XCH = (long)T_DIM * B_DIM * IN_DIM / 4;  // 4M float4 chunks of x
  if (tid < XCH) {
    float4 v = ((const float4*)x)[tid];
    long e = tid << 2;                 // flat element index: t*(B*IN) + b*IN + i
    int  i = (int)(e & (IN_DIM - 1));
    long tb = e >> 10;                 // t*B + b
    int  b = (int)(tb & (B_DIM - 1));
    long t = tb >> 3;
    ushort4 o;
    o.x = f2bf_rne(v.x); o.y = f2bf_rne(v.y); o.z = f2bf_rne(v.z); o.w = f2bf_rne(v.w);
    *(ushort4*)(xb + (((long)b * T_DIM + t) << 10) + i) = o;   // [B][T][IN]
  } else {
    long c = tid - XCH;                // weight chunk, identity layout
    float4 v = ((const float4*)w)[c];
    ushort4 o;
    o.x = f2bf_rne(v.x); o.y = f2bf_rne(v.y); o.z = f2bf_rne(v.z); o.w = f2bf_rne(v.w);
    ((ushort4*)wb)[c] = o;
  }
}

// One GEMM per blockIdx.z slot (b,k): C[t,o] = sum_i xb[b][t][i] * wb[sel[b,k]][o][i]
// Both operands K-contiguous (NT GEMM) -> identical fragment loads for A and B.
__global__ __launch_bounds__(256) void gemm_mod(
    const unsigned short* __restrict__ xb, const unsigned short* __restrict__ wb,
    const int* __restrict__ sel, float* __restrict__ out) {
  // Lane-contiguous LDS layout (required by global_load_lds wave-uniform base):
  // chunk c (16B) = row c>>2, cols ((c&3)*8..+8) -> byte offset c*16 == row-major [row][BK]
  __shared__ alignas(16) unsigned short As[BM * BK];
  __shared__ alignas(16) unsigned short Bs[BN * BK];

  const int nt = blockIdx.x;           // OUT tile: 0..7
  const int mt = blockIdx.y;           // T tile:   0..15
  const int bk = blockIdx.z;           // 0..15 -> (b, k)
  const int b  = bk >> 1;
  const int ks = bk & 1;
  const int expert = sel[bk];          // selection[b*K + k] == sel[bk]

  const unsigned short* A  = xb + ((long)b * T_DIM + (long)mt * BM) * IN_DIM;
  const unsigned short* Bw = wb + ((long)expert * OUT_DIM + (long)nt * BN) * IN_DIM;

  const int tid  = threadIdx.x;
  const int lane = tid & 63;
  const int c0 = tid, c1 = tid + 256;  // each thread stages 2 chunks per tile

  const int lm = lane & 15;            // MFMA m/n index
  const int kg = lane >> 4;            // MFMA k-group (0..3)

  const int wave = tid >> 6;           // 4 waves in 2x2 -> each computes 64x64
  const int wm = (wave >> 1) * 64;
  const int wn = (wave & 1) * 64;

  f32x4 acc[4][4];
  const f32x4 z = {0.f, 0.f, 0.f, 0.f};
  #pragma unroll
  for (int i = 0; i < 4; ++i)
    #pragma unroll
    for (int j = 0; j < 4; ++j) acc[i][j] = z;

  const long ga0 = (long)(c0 >> 2) * IN_DIM + (c0 & 3) * 8;  // element offsets
  const long ga1 = (long)(c1 >> 2) * IN_DIM + (c1 & 3) * 8;

  for (int kt = 0; kt < IN_DIM; kt += BK) {
    __syncthreads();                   // previous iter's ds_reads done before overwrite
    async_load16(A  + ga0 + kt, &As[c0 * 8]);
    async_load16(A  + ga1 + kt, &As[c1 * 8]);
    async_load16(Bw + ga0 + kt, &Bs[c0 * 8]);
    async_load16(Bw + ga1 + kt, &Bs[c1 * 8]);
    __syncthreads();                   // compiler drains vmcnt(0) before s_barrier

    bf16x8 af[4], bfr[4];
    #pragma unroll
    for (int mi = 0; mi < 4; ++mi)
      af[mi] = *(const bf16x8*)&As[(wm + mi * 16 + lm) * BK + kg * 8];
    #pragma unroll
    for (int ni = 0; ni < 4; ++ni)
      bfr[ni] = *(const bf16x8*)&Bs[(wn + ni * 16 + lm) * BK + kg * 8];

    #pragma unroll
    for (int mi = 0; mi < 4; ++mi)
      #pragma unroll
      for (int ni = 0; ni < 4; ++ni)
        acc[mi][ni] = __builtin_amdgcn_mfma_f32_16x16x32_bf16(af[mi], bfr[ni], acc[mi][ni], 0, 0, 0);
  }

  // Epilogue. C/D layout (m89-verified): col = lane&15, row = (lane>>4)*4 + reg
  const int row0 = mt * BM + wm + kg * 4;
  const int col0 = nt * BN + wn + lm;
  #pragma unroll
  for (int mi = 0; mi < 4; ++mi) {
    #pragma unroll
    for (int r = 0; r < 4; ++r) {
      const int t = row0 + mi * 16 + r;
      float* po = out + (long)t * (B_DIM * KSLOT * OUT_DIM)
                      + b * (KSLOT * OUT_DIM) + ks * OUT_DIM + col0;
      #pragma unroll
      for (int ni = 0; ni < 4; ++ni)
        po[ni * 16] = acc[mi][ni][r];
    }
  }
}

extern "C" void kernel_launch(void* const* d_in, const int* in_sizes, int n_in,
                              void* d_out, int out_size, void* d_ws, size_t ws_size,
                              hipStream_t stream) {
  const float* x   = (const float*)d_in[0];   // [T][B][IN] fp32
  const int*   sel = (const int*)d_in[1];     // [B][K] int32
  const float* w   = (const float*)d_in[2];   // [NMOD][OUT][IN] fp32
  float* out = (float*)d_out;                 // [T][B][K*OUT] fp32

  unsigned short* xb = (unsigned short*)d_ws;                       // 32 MiB bf16 [B][T][IN]
  unsigned short* wb = xb + (long)T_DIM * B_DIM * IN_DIM;           // 32 MiB bf16 [NMOD][OUT][IN]

  const long total_chunks =
      ((long)T_DIM * B_DIM * IN_DIM + (long)NMOD * OUT_DIM * IN_DIM) / 4;
  dim3 cgrid((unsigned)((total_chunks + 255) / 256));
  convert_repack<<<cgrid, 256, 0, stream>>>(x, w, xb, wb);

  dim3 ggrid(OUT_DIM / BN, T_DIM / BM, B_DIM * KSLOT);
  gemm_mod<<<ggrid, 256, 0, stream>>>(xb, wb, sel, out);
}